// Round 4
// baseline (251.751 us; speedup 1.0000x reference)
//
#include <hip/hip_runtime.h>

#define G_ 8
#define DIN 128
#define ACT 16
#define H1 600
#define H2 500
#define H1P 608
#define H2P 512
#define BT 128
#define NBLK 256
#define NCHUNK 19
#define NTHR 768

// ws offsets (bytes)
#define OFF_W2S 0
#define OFF_W1  622592
#define OFF_W2A 1867776
#define OFF_B1  1998848
#define OFF_B2S 2018304
#define OFF_W3  2020352
#define PREP_BYTES 2036736

// LDS (dynamic)
#define LDS_W2S 0u        // 3 x 32768 (tri-buffer W2s chunk slabs)
#define LDS_W1  98304u    // 3 x 8192  (tri-buffer W1 chunk slabs)
#define LDS_H1  122880u   // 2 x 8192  (h1 frag slabs, producer->consumer)
#define LDS_RED 139264u   // 4 x 128 x 4
#define LDS_IDX 141312u   // 128 ints
#define LDS_B1  141824u   // 8 x 608 x 4
#define LDS_TOTAL 161280

typedef __attribute__((ext_vector_type(8))) short short8;
typedef __attribute__((ext_vector_type(4))) float f32x4;
typedef __attribute__((ext_vector_type(16))) float f32x16;

__device__ __forceinline__ unsigned short f2bf(float f) {
  unsigned u = __float_as_uint(f);
  unsigned r = u + 0x7fffu + ((u >> 16) & 1u);
  return (unsigned short)(r >> 16);
}

__device__ __forceinline__ short8 pack8(const float* v) {
  short8 p;
#pragma unroll
  for (int j = 0; j < 8; ++j) p[j] = (short)f2bf(v[j]);
  return p;
}

__device__ __forceinline__ unsigned long long pack4(f32x4 v) {
  unsigned long long pk = 0;
#pragma unroll
  for (int j = 0; j < 4; ++j)
    pk |= (unsigned long long)f2bf(v[j]) << (16 * j);
  return pk;
}

__device__ __forceinline__ void stage1k(unsigned lds_off, const void* g) {
  __builtin_amdgcn_global_load_lds(
      (const __attribute__((address_space(1))) unsigned int*)(unsigned long long)g,
      (__attribute__((address_space(3))) unsigned int*)lds_off,
      16, 0, 0);
}

// ---------------- prep: coalesced-read / scatter-write frag images ----------------
// ws[0..PREP_BYTES) must be zeroed before this kernel (pads stay 0).
__global__ __launch_bounds__(256) void prep_kernel(
    const float* __restrict__ W1, const float* __restrict__ b1,
    const float* __restrict__ W2s, const float* __restrict__ b2s,
    const float* __restrict__ W2a, const float* __restrict__ W3,
    char* __restrict__ ws)
{
  unsigned long long* w2s_img = (unsigned long long*)(ws + OFF_W2S);
  unsigned long long* w1_img  = (unsigned long long*)(ws + OFF_W1);
  unsigned long long* w2a_img = (unsigned long long*)(ws + OFF_W2A);
  float* b1p  = (float*)(ws + OFF_B1);
  float* b2sp = (float*)(ws + OFF_B2S);
  float* w3p  = (float*)(ws + OFF_W3);
  const int tid = blockIdx.x * blockDim.x + threadIdx.x;
  const int nthr = gridDim.x * blockDim.x;

  // W2s: 500x600 f32, 75000 f32x4 units. image [chunk19][t2][ct16][lane64][8]
  for (int u = tid; u < 75000; u += nthr) {
    const int e0 = u * 4;
    const int c = e0 / 600, k0 = e0 - c * 600;
    f32x4 v = *(const f32x4*)(W2s + e0);
    const int chunk = k0 >> 5, t = (k0 >> 4) & 1, khi = (k0 >> 3) & 1, j0 = k0 & 7;
    const int l = (c & 31) + khi * 32, ct = c >> 5;
    const int base = ((chunk * 2 + t) * 16 + ct) * 64 + l;
    w2s_img[base * 2 + (j0 >> 2)] = pack4(v);
  }
  // W1: 8x600x128 f32, 153600 units. image [g][chunk19][ks4][ft2][lane64][8]
  for (int u = tid; u < 153600; u += nthr) {
    const int e0 = u * 4;
    const int g = e0 / 76800;
    const int rem = e0 - g * 76800;
    const int f = rem >> 7, d0 = rem & 127;
    f32x4 v = *(const f32x4*)(W1 + e0);
    const int chunk = f >> 5, ft = (f >> 4) & 1, fl = f & 15;
    const int ks = d0 >> 5, lhi = (d0 >> 3) & 3, j0 = d0 & 7;
    const int base = ((g * NCHUNK + chunk) * 8 + ks * 2 + ft) * 64 + (lhi * 16 + fl);
    w1_img[base * 2 + (j0 >> 2)] = pack4(v);
  }
  // W2a: 8x500x16 f32, 16000 units. image [g][ct16][lane64][8]
  for (int u = tid; u < 16000; u += nthr) {
    const int e0 = u * 4;
    const int g = e0 / 8000;
    const int rem = e0 - g * 8000;
    const int c = rem >> 4, a0 = rem & 15;
    f32x4 v = *(const f32x4*)(W2a + e0);
    const int khi = (a0 >> 3) & 1, j0 = a0 & 7;
    const int l = (c & 31) + khi * 32, ct = c >> 5;
    const int base = (g * 16 + ct) * 64 + l;
    w2a_img[base * 2 + (j0 >> 2)] = pack4(v);
  }
  for (int e = tid; e < G_ * H1; e += nthr) {
    const int g = e / H1, f = e - g * H1;
    b1p[g * H1P + f] = b1[e];
  }
  for (int e = tid; e < H2; e += nthr) b2sp[e] = b2s[e];
  for (int e = tid; e < G_ * H2; e += nthr) {
    const int g = e / H2, c = e - g * H2;
    w3p[g * H2P + c] = W3[e];
  }
}

// ---------------- fused: wave-specialized producer/consumer ----------------
// 256 blocks x 768 thr. Waves 0-3: layer-1 producers (32 samples each).
// Waves 4-11: layer-2 consumers, (cg=cw&3 -> 4 ct tiles = 128 cols, ng=cw>>2 -> 2 nt
// tiles = 64 samples), acc[4][2] f32x16.
__global__ __launch_bounds__(NTHR, 3) void critic_fused(
    const float* __restrict__ state, const float* __restrict__ action,
    const int* __restrict__ idx, const float* __restrict__ b3,
    const char* __restrict__ ws, float* __restrict__ out)
{
  extern __shared__ char smem[];
  const int tid = threadIdx.x, lane = tid & 63, w = tid >> 6;
  const int s0 = blockIdx.x * BT;
  int* idx_lds = (int*)(smem + LDS_IDX);
  float* b1lds = (float*)(smem + LDS_B1);
  float* red   = (float*)(smem + LDS_RED);

  const unsigned short* w1img  = (const unsigned short*)(ws + OFF_W1);
  const unsigned short* w2aimg = (const unsigned short*)(ws + OFF_W2A);
  const float* b1p  = (const float*)(ws + OFF_B1);
  const float* b2sp = (const float*)(ws + OFF_B2S);
  const float* w3p  = (const float*)(ws + OFF_W3);
  const char* w2ssrc = ws + OFF_W2S;

  if (tid < BT) idx_lds[tid] = idx[s0 + tid];
  for (int u = tid; u < (G_ * H1P) / 4; u += NTHR)
    *(f32x4*)(b1lds + u * 4) = *(const f32x4*)(b1p + u * 4);
  __syncthreads();
  const int g_lo = idx_lds[0], g_hi = idx_lds[BT - 1];

  const int cw = w - 4, cg = cw & 3, ng = cw >> 2;
  f32x16 acc[4][2];

  if (w < 4) {
    // ========== PRODUCER ==========
    const int p = w;
    int myg[2];
    short8 bs[2][4];
#pragma unroll
    for (int nti = 0; nti < 2; ++nti) {
      myg[nti] = idx_lds[(p * 2 + nti) * 16 + (lane & 15)];
      const float* sp = state + (size_t)(s0 + (p * 2 + nti) * 16 + (lane & 15)) * DIN + ((lane >> 4) << 3);
#pragma unroll
      for (int ks = 0; ks < 4; ++ks) {
        float v[8];
        f32x4 t0 = *(const f32x4*)(sp + ks * 32), t1 = *(const f32x4*)(sp + ks * 32 + 4);
        v[0]=t0[0];v[1]=t0[1];v[2]=t0[2];v[3]=t0[3];
        v[4]=t1[0];v[5]=t1[1];v[6]=t1[2];v[7]=t1[3];
        bs[nti][ks] = pack8(v);
      }
    }
    const char* w1src = (const char*)w1img + (size_t)g_lo * NCHUNK * 8192;
#pragma unroll
    for (int c = 0; c < 3; ++c)
#pragma unroll
      for (int u = 0; u < 2; ++u)
        stage1k(LDS_W1 + (unsigned)(c * 8192 + p * 2048 + u * 1024 + lane * 16),
                w1src + c * 8192 + p * 2048 + u * 1024 + lane * 16);

    auto produce = [&](int c, int hb, int rbuf) {
      f32x4 kept[2][2];
#pragma unroll
      for (int a = 0; a < 2; ++a)
#pragma unroll
        for (int f = 0; f < 2; ++f) { kept[a][f][0]=0.f;kept[a][f][1]=0.f;kept[a][f][2]=0.f;kept[a][f][3]=0.f; }
      for (int g = g_lo; g <= g_hi; ++g) {
        f32x4 a1[2][2];
#pragma unroll
        for (int a = 0; a < 2; ++a)
#pragma unroll
          for (int f = 0; f < 2; ++f) { a1[a][f][0]=0.f;a1[a][f][1]=0.f;a1[a][f][2]=0.f;a1[a][f][3]=0.f; }
#pragma unroll
        for (int ks = 0; ks < 4; ++ks)
#pragma unroll
          for (int ft = 0; ft < 2; ++ft) {
            short8 aw;
            if (g == g_lo)
              aw = *(const short8*)(smem + LDS_W1 + (unsigned)(rbuf * 8192 + ((ks * 2 + ft) * 64 + lane) * 16));
            else
              aw = *(const short8*)(w1img + (((size_t)(g * NCHUNK + c) * 8 + ks * 2 + ft) * 64 + lane) * 8);
#pragma unroll
            for (int nti = 0; nti < 2; ++nti)
              a1[nti][ft] = __builtin_amdgcn_mfma_f32_16x16x32_bf16(aw, bs[nti][ks], a1[nti][ft], 0, 0, 0);
          }
#pragma unroll
        for (int nti = 0; nti < 2; ++nti)
          if (myg[nti] == g) { kept[nti][0] = a1[nti][0]; kept[nti][1] = a1[nti][1]; }
      }
      const int kloc = (lane >> 4) << 2, khalf = lane >> 5, j0 = kloc & 7;
#pragma unroll
      for (int nti = 0; nti < 2; ++nti)
#pragma unroll
        for (int ft = 0; ft < 2; ++ft) {
          const int f0 = c * 32 + ft * 16 + kloc;
          f32x4 bv = *(const f32x4*)(b1lds + myg[nti] * H1P + f0);
          unsigned long long pk = 0;
#pragma unroll
          for (int r = 0; r < 4; ++r) {
            float hv = fmaxf(kept[nti][ft][r] + bv[r], 0.f);
            pk |= (unsigned long long)f2bf(hv) << (16 * r);
          }
          *(unsigned long long*)(smem + LDS_H1 + (unsigned)(hb * 8192 +
              (ft * 4 + p) * 1024 + (khalf * 32 + nti * 16 + (lane & 15)) * 16 + j0 * 2)) = pk;
        }
    };

    asm volatile("s_waitcnt vmcnt(2)" ::: "memory");   // c0 landed (c1,c2 in flight)
    __builtin_amdgcn_sched_barrier(0);
    __builtin_amdgcn_s_barrier();                      // barrier 1
    produce(0, 0, 0);
    asm volatile("s_waitcnt lgkmcnt(0)" ::: "memory");
    __builtin_amdgcn_sched_barrier(0);
    __builtin_amdgcn_s_barrier();                      // barrier 2

    int wb = 0, rb = 1;   // wb = i%3 (target for chunk i+3), rb = (i+1)%3
    for (int i = 0; i < NCHUNK; ++i) {
      if (i < NCHUNK - 3)
#pragma unroll
        for (int u = 0; u < 2; ++u)
          stage1k(LDS_W1 + (unsigned)(wb * 8192 + p * 2048 + u * 1024 + lane * 16),
                  w1src + (size_t)(i + 3) * 8192 + p * 2048 + u * 1024 + lane * 16);
      if (i + 1 < NCHUNK) produce(i + 1, (i + 1) & 1, rb);
      asm volatile("s_waitcnt lgkmcnt(0)" ::: "memory");
      if (i < NCHUNK - 3)       { asm volatile("s_waitcnt vmcnt(2)" ::: "memory"); }
      else if (i == NCHUNK - 3) { asm volatile("s_waitcnt vmcnt(0)" ::: "memory"); }
      __builtin_amdgcn_sched_barrier(0);
      __builtin_amdgcn_s_barrier();
      wb = wb == 2 ? 0 : wb + 1;
      rb = rb == 2 ? 0 : rb + 1;
    }
  } else {
    // ========== CONSUMER ==========
    short8 bact[2];
#pragma unroll
    for (int nti = 0; nti < 2; ++nti) {
      const float* ap = action + (size_t)(s0 + (ng * 2 + nti) * 32 + (lane & 31)) * ACT + ((lane >> 5) << 3);
      float v[8];
      f32x4 a0 = *(const f32x4*)ap, a1 = *(const f32x4*)(ap + 4);
      v[0]=a0[0];v[1]=a0[1];v[2]=a0[2];v[3]=a0[3];
      v[4]=a1[0];v[5]=a1[1];v[6]=a1[2];v[7]=a1[3];
      bact[nti] = pack8(v);
    }
#pragma unroll
    for (int c = 0; c < 2; ++c)
#pragma unroll
      for (int u = 0; u < 4; ++u)
        stage1k(LDS_W2S + (unsigned)(c * 32768 + cw * 4096 + u * 1024 + lane * 16),
                w2ssrc + c * 32768 + cw * 4096 + u * 1024 + lane * 16);

#pragma unroll
    for (int c4 = 0; c4 < 4; ++c4)
#pragma unroll
      for (int nti = 0; nti < 2; ++nti)
#pragma unroll
        for (int r = 0; r < 16; ++r) acc[c4][nti][r] = 0.f;
    for (int g = g_lo; g <= g_hi; ++g) {
      bool sel[2];
#pragma unroll
      for (int nti = 0; nti < 2; ++nti)
        sel[nti] = (idx_lds[(ng * 2 + nti) * 32 + (lane & 31)] == g);
#pragma unroll
      for (int c4 = 0; c4 < 4; ++c4) {
        short8 af = *(const short8*)(w2aimg + (((size_t)g * 16 + cg * 4 + c4) * 64 + lane) * 8);
#pragma unroll
        for (int nti = 0; nti < 2; ++nti) {
          f32x16 z;
#pragma unroll
          for (int r = 0; r < 16; ++r) z[r] = 0.f;
          f32x16 t = __builtin_amdgcn_mfma_f32_32x32x16_bf16(af, bact[nti], z, 0, 0, 0);
#pragma unroll
          for (int r = 0; r < 16; ++r) acc[c4][nti][r] = sel[nti] ? t[r] : acc[c4][nti][r];
        }
      }
    }
    asm volatile("s_waitcnt vmcnt(4)" ::: "memory");   // c0 landed
    __builtin_amdgcn_sched_barrier(0);
    __builtin_amdgcn_s_barrier();                      // barrier 1
    __builtin_amdgcn_s_barrier();                      // barrier 2

    int sb = 2, rb2 = 0;  // sb = (i+2)%3 stage target, rb2 = i%3 read buf
    for (int i = 0; i < NCHUNK; ++i) {
      if (i < NCHUNK - 2)
#pragma unroll
        for (int u = 0; u < 4; ++u)
          stage1k(LDS_W2S + (unsigned)(sb * 32768 + cw * 4096 + u * 1024 + lane * 16),
                  w2ssrc + (size_t)(i + 2) * 32768 + cw * 4096 + u * 1024 + lane * 16);
      const unsigned wbo = LDS_W2S + (unsigned)(rb2 * 32768);
      const unsigned hbo = LDS_H1 + (unsigned)((i & 1) * 8192);
      short8 af[2][4], bf[2][2];
#pragma unroll
      for (int t = 0; t < 2; ++t) {
#pragma unroll
        for (int c4 = 0; c4 < 4; ++c4)
          af[t][c4] = *(const short8*)(smem + wbo + (unsigned)(((t * 16 + cg * 4 + c4) * 64 + lane) * 16));
#pragma unroll
        for (int nti = 0; nti < 2; ++nti)
          bf[t][nti] = *(const short8*)(smem + hbo + (unsigned)(((t * 4 + ng * 2 + nti) * 64 + lane) * 16));
      }
      __builtin_amdgcn_s_setprio(1);
#pragma unroll
      for (int t = 0; t < 2; ++t)
#pragma unroll
        for (int c4 = 0; c4 < 4; ++c4)
#pragma unroll
          for (int nti = 0; nti < 2; ++nti)
            acc[c4][nti] = __builtin_amdgcn_mfma_f32_32x32x16_bf16(af[t][c4], bf[t][nti], acc[c4][nti], 0, 0, 0);
      __builtin_amdgcn_s_setprio(0);
      if (i < NCHUNK - 2)       { asm volatile("s_waitcnt vmcnt(4)" ::: "memory"); }
      else if (i == NCHUNK - 2) { asm volatile("s_waitcnt vmcnt(0)" ::: "memory"); }
      __builtin_amdgcn_sched_barrier(0);
      __builtin_amdgcn_s_barrier();
      sb = sb == 2 ? 0 : sb + 1;
      rb2 = rb2 == 2 ? 0 : rb2 + 1;
    }
  }

  __syncthreads();
  if (w >= 4) {
    float qp[2] = {0.f, 0.f};
    int gs[2];
#pragma unroll
    for (int nti = 0; nti < 2; ++nti) gs[nti] = idx_lds[(ng * 2 + nti) * 32 + (lane & 31)];
#pragma unroll
    for (int c4 = 0; c4 < 4; ++c4) {
      const int cbase = cg * 128 + c4 * 32 + ((lane >> 5) << 2);
#pragma unroll
      for (int r = 0; r < 16; ++r) {
        const int c = cbase + (r & 3) + ((r >> 2) << 3);
        const float b2v = b2sp[c];
#pragma unroll
        for (int nti = 0; nti < 2; ++nti) {
          float v2 = fmaxf(acc[c4][nti][r] + b2v, 0.f);
          qp[nti] += v2 * w3p[gs[nti] * H2P + c];
        }
      }
    }
#pragma unroll
    for (int nti = 0; nti < 2; ++nti) {
      float v = qp[nti] + __shfl_xor(qp[nti], 32, 64);
      if (lane < 32) red[cg * BT + (ng * 2 + nti) * 32 + lane] = v;
    }
  }
  __syncthreads();
  if (tid < BT) {
    out[s0 + tid] = red[tid] + red[BT + tid] + red[2 * BT + tid] + red[3 * BT + tid]
                  + b3[idx_lds[tid]];
  }
}

extern "C" void kernel_launch(void* const* d_in, const int* in_sizes, int n_in,
                              void* d_out, int out_size, void* d_ws, size_t ws_size,
                              hipStream_t stream) {
  const float* state  = (const float*)d_in[0];
  const float* action = (const float*)d_in[1];
  const int*   idx    = (const int*)d_in[2];
  const float* W1     = (const float*)d_in[3];
  const float* b1     = (const float*)d_in[4];
  const float* W2s    = (const float*)d_in[5];
  const float* b2s    = (const float*)d_in[6];
  const float* W2a    = (const float*)d_in[7];
  const float* W3     = (const float*)d_in[8];
  const float* b3     = (const float*)d_in[9];
  float* out = (float*)d_out;
  char* ws = (char*)d_ws;

  (void)hipFuncSetAttribute((const void*)critic_fused,
                            hipFuncAttributeMaxDynamicSharedMemorySize, LDS_TOTAL);
  hipMemsetAsync(ws, 0, PREP_BYTES, stream);
  hipLaunchKernelGGL(prep_kernel, dim3(1024), dim3(256), 0, stream,
                     W1, b1, W2s, b2s, W2a, W3, ws);
  hipLaunchKernelGGL(critic_fused, dim3(NBLK), dim3(NTHR), LDS_TOTAL, stream,
                     state, action, idx, b3, ws, out);
}

// Round 5
// 126.258 us; speedup vs baseline: 1.9939x; 1.9939x over previous
//
#include <hip/hip_runtime.h>

#define G_ 8
#define DIN 128
#define ACT 16
#define H1 600
#define H2 500
#define H1P 608
#define H2P 512
#define BT 128
#define NBLK 256
#define NCHUNK 19
#define NTHR 512

// ws offsets (bytes)
#define OFF_W2S 0
#define OFF_W1  622592
#define OFF_W2A 1867776
#define OFF_B1  1998848
#define OFF_B2S 2018304
#define OFF_W3  2020352
#define PREP_BYTES 2036736

// LDS (dynamic)
#define LDS_H1  0u        // 2 x 8192 : [buf][t*4+nt][lane]*16B  (h1 handoff dbuf)
#define LDS_W1  16384u    // 2 x 8192 : [buf][ks*2+ft][lane]*16B (W1 chunk dbuf)
#define LDS_B1  32768u    // 8 x 608 x 4 = 19456
#define LDS_IDX 52224u    // 128 ints
#define LDS_RED 52736u    // 8 x 128 x 4 = 4096
#define LDS_TOTAL 56832

typedef __attribute__((ext_vector_type(8))) short short8;
typedef __attribute__((ext_vector_type(4))) float f32x4;
typedef __attribute__((ext_vector_type(16))) float f32x16;

__device__ __forceinline__ unsigned short f2bf(float f) {
  unsigned u = __float_as_uint(f);
  unsigned r = u + 0x7fffu + ((u >> 16) & 1u);
  return (unsigned short)(r >> 16);
}

__device__ __forceinline__ short8 pack8(const float* v) {
  short8 p;
#pragma unroll
  for (int j = 0; j < 8; ++j) p[j] = (short)f2bf(v[j]);
  return p;
}

__device__ __forceinline__ unsigned long long pack4(f32x4 v) {
  unsigned long long pk = 0;
#pragma unroll
  for (int j = 0; j < 4; ++j)
    pk |= (unsigned long long)f2bf(v[j]) << (16 * j);
  return pk;
}

__device__ __forceinline__ void stage1k(unsigned lds_off, const void* g) {
  __builtin_amdgcn_global_load_lds(
      (const __attribute__((address_space(1))) unsigned int*)(unsigned long long)g,
      (__attribute__((address_space(3))) unsigned int*)lds_off,
      16, 0, 0);
}

// ---------------- prep: coalesced-read / scatter-write frag images ----------------
// ws[0..PREP_BYTES) zeroed before this kernel (pads stay 0).
__global__ __launch_bounds__(256) void prep_kernel(
    const float* __restrict__ W1, const float* __restrict__ b1,
    const float* __restrict__ W2s, const float* __restrict__ b2s,
    const float* __restrict__ W2a, const float* __restrict__ W3,
    char* __restrict__ ws)
{
  unsigned long long* w2s_img = (unsigned long long*)(ws + OFF_W2S);
  unsigned long long* w1_img  = (unsigned long long*)(ws + OFF_W1);
  unsigned long long* w2a_img = (unsigned long long*)(ws + OFF_W2A);
  float* b1p  = (float*)(ws + OFF_B1);
  float* b2sp = (float*)(ws + OFF_B2S);
  float* w3p  = (float*)(ws + OFF_W3);
  const int tid = blockIdx.x * blockDim.x + threadIdx.x;
  const int nthr = gridDim.x * blockDim.x;

  // W2s: 500x600 f32. image [chunk19][t2][ct16][lane64][8bf16]
  for (int u = tid; u < 75000; u += nthr) {
    const int e0 = u * 4;
    const int c = e0 / 600, k0 = e0 - c * 600;
    f32x4 v = *(const f32x4*)(W2s + e0);
    const int chunk = k0 >> 5, t = (k0 >> 4) & 1, khi = (k0 >> 3) & 1, j0 = k0 & 7;
    const int l = (c & 31) + khi * 32, ct = c >> 5;
    const int base = ((chunk * 2 + t) * 16 + ct) * 64 + l;
    w2s_img[base * 2 + (j0 >> 2)] = pack4(v);
  }
  // W1: 8x600x128 f32. image [g][chunk19][ks4][ft2][lane64][8bf16]
  for (int u = tid; u < 153600; u += nthr) {
    const int e0 = u * 4;
    const int g = e0 / 76800;
    const int rem = e0 - g * 76800;
    const int f = rem >> 7, d0 = rem & 127;
    f32x4 v = *(const f32x4*)(W1 + e0);
    const int chunk = f >> 5, ft = (f >> 4) & 1, fl = f & 15;
    const int ks = d0 >> 5, lhi = (d0 >> 3) & 3, j0 = d0 & 7;
    const int base = ((g * NCHUNK + chunk) * 8 + ks * 2 + ft) * 64 + (lhi * 16 + fl);
    w1_img[base * 2 + (j0 >> 2)] = pack4(v);
  }
  // W2a: 8x500x16 f32. image [g][ct16][lane64][8bf16]
  for (int u = tid; u < 16000; u += nthr) {
    const int e0 = u * 4;
    const int g = e0 / 8000;
    const int rem = e0 - g * 8000;
    const int c = rem >> 4, a0 = rem & 15;
    f32x4 v = *(const f32x4*)(W2a + e0);
    const int khi = (a0 >> 3) & 1, j0 = a0 & 7;
    const int l = (c & 31) + khi * 32, ct = c >> 5;
    const int base = (g * 16 + ct) * 64 + l;
    w2a_img[base * 2 + (j0 >> 2)] = pack4(v);
  }
  for (int e = tid; e < G_ * H1; e += nthr) {
    const int g = e / H1, f = e - g * H1;
    b1p[g * H1P + f] = b1[e];
  }
  for (int e = tid; e < H2; e += nthr) b2sp[e] = b2s[e];
  for (int e = tid; e < G_ * H2; e += nthr) {
    const int g = e / H2, c = e - g * H2;
    w3p[g * H2P + c] = W3[e];
  }
}

// ---------------- fused single-path kernel, counted-vmcnt pipeline ----------------
// 256 blocks x 512 thr (1/CU). Wave w: layer2 ct {2w,2w+1} x nt 0..3 (acc[2][4]);
// layer1 producer for samples w*16..w*16+15.
__global__ __launch_bounds__(NTHR, 2) void critic_fused(
    const float* __restrict__ state, const float* __restrict__ action,
    const int* __restrict__ idx, const float* __restrict__ b3,
    const char* __restrict__ ws, float* __restrict__ out)
{
  extern __shared__ char smem[];
  const int tid = threadIdx.x, lane = tid & 63, w = tid >> 6;
  const int s0 = blockIdx.x * BT;
  int* idx_lds = (int*)(smem + LDS_IDX);
  float* b1lds = (float*)(smem + LDS_B1);
  float* red   = (float*)(smem + LDS_RED);

  const unsigned short* w2simg = (const unsigned short*)(ws + OFF_W2S);
  const unsigned short* w1img  = (const unsigned short*)(ws + OFF_W1);
  const unsigned short* w2aimg = (const unsigned short*)(ws + OFF_W2A);
  const float* b1p  = (const float*)(ws + OFF_B1);
  const float* b2sp = (const float*)(ws + OFF_B2S);
  const float* w3p  = (const float*)(ws + OFF_W3);

  if (tid < BT) idx_lds[tid] = idx[s0 + tid];
  for (int u = tid; u < (G_ * H1P) / 4; u += NTHR)
    ((f32x4*)b1lds)[u] = ((const f32x4*)b1p)[u];
  __syncthreads();
  const int g_lo = idx_lds[0], g_hi = idx_lds[BT - 1];
  const int myg  = idx_lds[w * 16 + (lane & 15)];

  // state B-frags (16x16x32: sample = lane&15, k = (lane>>4)*8+j)
  short8 bs[4];
  {
    const float* sp = state + (size_t)(s0 + w * 16 + (lane & 15)) * DIN + ((lane >> 4) << 3);
#pragma unroll
    for (int ks = 0; ks < 4; ++ks) {
      float v[8];
      f32x4 t0 = *(const f32x4*)(sp + ks * 32), t1 = *(const f32x4*)(sp + ks * 32 + 4);
      v[0]=t0[0];v[1]=t0[1];v[2]=t0[2];v[3]=t0[3];
      v[4]=t1[0];v[5]=t1[1];v[6]=t1[2];v[7]=t1[3];
      bs[ks] = pack8(v);
    }
  }
  // action B-frags (32x32x16: sample = lane&31, k = (lane>>5)*8+j)
  short8 bact[4];
#pragma unroll
  for (int nt = 0; nt < 4; ++nt) {
    const float* ap = action + (size_t)(s0 + nt * 32 + (lane & 31)) * ACT + ((lane >> 5) << 3);
    float v[8];
    f32x4 a0 = *(const f32x4*)ap, a1 = *(const f32x4*)(ap + 4);
    v[0]=a0[0];v[1]=a0[1];v[2]=a0[2];v[3]=a0[3];
    v[4]=a1[0];v[5]=a1[1];v[6]=a1[2];v[7]=a1[3];
    bact[nt] = pack8(v);
  }

  const char* w1src = (const char*)(ws + OFF_W1) + (size_t)g_lo * NCHUNK * 8192;
  // W1 chunks 0,1 -> LDS dbuf (1 x 16B load/thread each)
  stage1k(LDS_W1 + (unsigned)(tid * 16), w1src + tid * 16);
  stage1k(LDS_W1 + (unsigned)(8192 + tid * 16), w1src + 8192 + tid * 16);

  // af(0) W2s frags -> regs
  short8 afc[2][2], afn[2][2];
#pragma unroll
  for (int t = 0; t < 2; ++t)
#pragma unroll
    for (int cti = 0; cti < 2; ++cti)
      afc[t][cti] = *(const short8*)(w2simg + ((((size_t)0 * 2 + t) * 16 + w * 2 + cti) * 64 + lane) * 8);

  // acc init: h2a = W2a[g].action, per-sample masked
  f32x16 acc[2][4];
#pragma unroll
  for (int a = 0; a < 2; ++a)
#pragma unroll
    for (int n = 0; n < 4; ++n)
#pragma unroll
      for (int r = 0; r < 16; ++r) acc[a][n][r] = 0.f;
  for (int g = g_lo; g <= g_hi; ++g) {
#pragma unroll
    for (int cti = 0; cti < 2; ++cti) {
      short8 af = *(const short8*)(w2aimg + (((size_t)g * 16 + w * 2 + cti) * 64 + lane) * 8);
#pragma unroll
      for (int nt = 0; nt < 4; ++nt) {
        f32x16 z;
#pragma unroll
        for (int r = 0; r < 16; ++r) z[r] = 0.f;
        f32x16 t = __builtin_amdgcn_mfma_f32_32x32x16_bf16(af, bact[nt], z, 0, 0, 0);
        const bool p = (idx_lds[nt * 32 + (lane & 31)] == g);
#pragma unroll
        for (int r = 0; r < 16; ++r) acc[cti][nt][r] = p ? t[r] : acc[cti][nt][r];
      }
    }
  }

  // layer-1 for chunk c -> h1buf[buf]; W1 from LDS buf (g_lo) / L2 (other games)
  auto produce = [&](int c, int buf) {
    f32x4 kept[2];
#pragma unroll
    for (int f = 0; f < 2; ++f) { kept[f][0]=0.f;kept[f][1]=0.f;kept[f][2]=0.f;kept[f][3]=0.f; }
    for (int g = g_lo; g <= g_hi; ++g) {
      f32x4 a1[2];
#pragma unroll
      for (int f = 0; f < 2; ++f) { a1[f][0]=0.f;a1[f][1]=0.f;a1[f][2]=0.f;a1[f][3]=0.f; }
#pragma unroll
      for (int ks = 0; ks < 4; ++ks)
#pragma unroll
        for (int ft = 0; ft < 2; ++ft) {
          short8 aw;
          if (g == g_lo)
            aw = *(const short8*)(smem + LDS_W1 + (unsigned)(buf * 8192 + ((ks * 2 + ft) * 64 + lane) * 16));
          else
            aw = *(const short8*)(w1img + (((size_t)(g * NCHUNK + c) * 8 + ks * 2 + ft) * 64 + lane) * 8);
          a1[ft] = __builtin_amdgcn_mfma_f32_16x16x32_bf16(aw, bs[ks], a1[ft], 0, 0, 0);
        }
      if (myg == g) { kept[0] = a1[0]; kept[1] = a1[1]; }
    }
    const int kloc = (lane >> 4) << 2, khalf = lane >> 5;
    const int nt = w >> 1, s32 = (w & 1) * 16 + (lane & 15);
#pragma unroll
    for (int ft = 0; ft < 2; ++ft) {
      const int f0 = c * 32 + ft * 16 + kloc;
      f32x4 bv = *(const f32x4*)(b1lds + myg * H1P + f0);
      unsigned long long pk = 0;
#pragma unroll
      for (int r = 0; r < 4; ++r) {
        float hv = fmaxf(kept[ft][r] + bv[r], 0.f);
        pk |= (unsigned long long)f2bf(hv) << (16 * r);
      }
      *(unsigned long long*)(smem + LDS_H1 + (unsigned)(buf * 8192 +
          (ft * 4 + nt) * 1024 + (khalf * 32 + s32) * 16 + (kloc & 7) * 2)) = pk;
    }
  };

  // prologue: drain once (stages 0,1 + af(0) + bs/bact landed), produce(0)
  asm volatile("s_waitcnt vmcnt(0)" ::: "memory");
  __builtin_amdgcn_sched_barrier(0);
  produce(0, 0);
  asm volatile("s_waitcnt lgkmcnt(0)" ::: "memory");
  __builtin_amdgcn_sched_barrier(0);
  __builtin_amdgcn_s_barrier();

  // main loop: one barrier per chunk, vmcnt never drained to 0
  for (int i = 0; i < NCHUNK; ++i) {
    const int cur = i & 1;
    if (i + 2 < NCHUNK)
      stage1k(LDS_W1 + (unsigned)(cur * 8192 + tid * 16),
              w1src + (size_t)(i + 2) * 8192 + tid * 16);
    if (i + 1 < NCHUNK) {
#pragma unroll
      for (int t = 0; t < 2; ++t)
#pragma unroll
        for (int cti = 0; cti < 2; ++cti)
          afn[t][cti] = *(const short8*)(w2simg + ((((size_t)(i + 1) * 2 + t) * 16 + w * 2 + cti) * 64 + lane) * 8);
    }
    // consume chunk i
    short8 bf[2][4];
#pragma unroll
    for (int t = 0; t < 2; ++t)
#pragma unroll
      for (int nt = 0; nt < 4; ++nt)
        bf[t][nt] = *(const short8*)(smem + LDS_H1 + (unsigned)(cur * 8192 + ((t * 4 + nt) * 64 + lane) * 16));
    __builtin_amdgcn_s_setprio(1);
#pragma unroll
    for (int t = 0; t < 2; ++t)
#pragma unroll
      for (int cti = 0; cti < 2; ++cti)
#pragma unroll
        for (int nt = 0; nt < 4; ++nt)
          acc[cti][nt] = __builtin_amdgcn_mfma_f32_32x32x16_bf16(afc[t][cti], bf[t][nt], acc[cti][nt], 0, 0, 0);
    __builtin_amdgcn_s_setprio(0);
    // produce chunk i+1 (W1(i+1) guaranteed by counted vmcnt: younger ops = S(i+2)+af(i+1))
    if (i + 1 < NCHUNK) {
      if (i + 2 < NCHUNK) { asm volatile("s_waitcnt vmcnt(5)" ::: "memory"); }
      else                { asm volatile("s_waitcnt vmcnt(4)" ::: "memory"); }
      __builtin_amdgcn_sched_barrier(0);
      produce(i + 1, cur ^ 1);
    }
    asm volatile("s_waitcnt lgkmcnt(0)" ::: "memory");
    __builtin_amdgcn_sched_barrier(0);
    __builtin_amdgcn_s_barrier();
#pragma unroll
    for (int t = 0; t < 2; ++t)
#pragma unroll
      for (int cti = 0; cti < 2; ++cti)
        afc[t][cti] = afn[t][cti];
  }

  // epilogue: bias + relu + W3[g] dot, LDS reduce, plain store
  float qp[4] = {0.f, 0.f, 0.f, 0.f};
  int gs[4];
#pragma unroll
  for (int nt = 0; nt < 4; ++nt) gs[nt] = idx_lds[nt * 32 + (lane & 31)];
#pragma unroll
  for (int cti = 0; cti < 2; ++cti) {
    const int cbase = (w * 2 + cti) * 32 + ((lane >> 5) << 2);
#pragma unroll
    for (int r = 0; r < 16; ++r) {
      const int c = cbase + (r & 3) + ((r >> 2) << 3);
      const float b2v = b2sp[c];
#pragma unroll
      for (int nt = 0; nt < 4; ++nt) {
        float v2 = fmaxf(acc[cti][nt][r] + b2v, 0.f);
        qp[nt] += v2 * w3p[gs[nt] * H2P + c];
      }
    }
  }
#pragma unroll
  for (int nt = 0; nt < 4; ++nt) {
    float v = qp[nt] + __shfl_xor(qp[nt], 32, 64);
    if (lane < 32) red[w * BT + nt * 32 + lane] = v;
  }
  __syncthreads();
  if (tid < BT) {
    float s = 0.f;
#pragma unroll
    for (int ww = 0; ww < 8; ++ww) s += red[ww * BT + tid];
    out[s0 + tid] = s + b3[idx_lds[tid]];
  }
}

extern "C" void kernel_launch(void* const* d_in, const int* in_sizes, int n_in,
                              void* d_out, int out_size, void* d_ws, size_t ws_size,
                              hipStream_t stream) {
  const float* state  = (const float*)d_in[0];
  const float* action = (const float*)d_in[1];
  const int*   idx    = (const int*)d_in[2];
  const float* W1     = (const float*)d_in[3];
  const float* b1     = (const float*)d_in[4];
  const float* W2s    = (const float*)d_in[5];
  const float* b2s    = (const float*)d_in[6];
  const float* W2a    = (const float*)d_in[7];
  const float* W3     = (const float*)d_in[8];
  const float* b3     = (const float*)d_in[9];
  float* out = (float*)d_out;
  char* ws = (char*)d_ws;

  hipMemsetAsync(ws, 0, PREP_BYTES, stream);
  hipLaunchKernelGGL(prep_kernel, dim3(1024), dim3(256), 0, stream,
                     W1, b1, W2s, b2s, W2a, W3, ws);
  hipLaunchKernelGGL(critic_fused, dim3(NBLK), dim3(NTHR), LDS_TOTAL, stream,
                     state, action, idx, b3, ws, out);
}

// Round 6
// 118.455 us; speedup vs baseline: 2.1253x; 1.0659x over previous
//
#include <hip/hip_runtime.h>

#define G_ 8
#define DIN 128
#define ACT 16
#define H1 600
#define H2 500
#define H2P 512
#define B1S 768           // padded per-game b1 stride (floats)
#define BT 128
#define NBLK 256
#define NCHUNK 19
#define NPHASE 9
#define NTHR 512

// ws offsets (bytes)
#define OFF_W2S 0
#define OFF_W1  622592
#define OFF_W2A 1867776
#define OFF_B1  1998848
#define OFF_B2S 2023424
#define OFF_W3  2025472

// LDS (dynamic)
#define LDS_H1  0u         // 4 x 8192 : [c&3][t*4+nt][lane]*16B
#define LDS_W1  32768u     // 8 x 8192 : [(c&3)*2+side][ks*2+ft][lane]*16B
#define LDS_B1  98304u     // 8 x 768 f32 = 24576
#define LDS_IDX 122880u    // 128 ints
#define LDS_RED 123392u    // 8*128*4
#define LDS_TOTAL 127488

typedef __attribute__((ext_vector_type(8))) short short8;
typedef __attribute__((ext_vector_type(4))) float f32x4;
typedef __attribute__((ext_vector_type(16))) float f32x16;

__device__ __forceinline__ unsigned short f2bf(float f) {
  unsigned u = __float_as_uint(f);
  unsigned r = u + 0x7fffu + ((u >> 16) & 1u);
  return (unsigned short)(r >> 16);
}

__device__ __forceinline__ short8 pack8(const float* v) {
  short8 p;
#pragma unroll
  for (int j = 0; j < 8; ++j) p[j] = (short)f2bf(v[j]);
  return p;
}

__device__ __forceinline__ void stage1k(unsigned lds_off, const void* g) {
  __builtin_amdgcn_global_load_lds(
      (const __attribute__((address_space(1))) unsigned int*)(unsigned long long)g,
      (__attribute__((address_space(3))) unsigned int*)lds_off,
      16, 0, 0);
}

// ---------------- prep: image-ordered, OOB -> 0 (no memset needed) ----------------
__global__ __launch_bounds__(256) void prep_kernel(
    const float* __restrict__ W1, const float* __restrict__ b1,
    const float* __restrict__ W2s, const float* __restrict__ b2s,
    const float* __restrict__ W2a, const float* __restrict__ W3,
    char* __restrict__ ws)
{
  short8* w2s_img = (short8*)(ws + OFF_W2S);
  short8* w1_img  = (short8*)(ws + OFF_W1);
  short8* w2a_img = (short8*)(ws + OFF_W2A);
  f32x4* b1p  = (f32x4*)(ws + OFF_B1);
  f32x4* b2sp = (f32x4*)(ws + OFF_B2S);
  f32x4* w3p  = (f32x4*)(ws + OFF_W3);
  const int tid = blockIdx.x * blockDim.x + threadIdx.x;
  const int nthr = gridDim.x * blockDim.x;

  // W2s image slots: [chunk19][t2][ct16][lane64]
  for (int s = tid; s < 38912; s += nthr) {
    const int chunk = s >> 11, t = (s >> 10) & 1, ct = (s >> 6) & 15, l = s & 63;
    const int c  = ct * 32 + (l & 31);
    const int k0 = chunk * 32 + t * 16 + ((l >> 5) << 3);
    float v[8];
    if (c < H2 && k0 < H1) {
      const float* p = W2s + (size_t)c * H1 + k0;
      f32x4 a0 = *(const f32x4*)p, a1 = *(const f32x4*)(p + 4);
      v[0]=a0[0];v[1]=a0[1];v[2]=a0[2];v[3]=a0[3];
      v[4]=a1[0];v[5]=a1[1];v[6]=a1[2];v[7]=a1[3];
    } else {
#pragma unroll
      for (int j = 0; j < 8; ++j) v[j] = 0.f;
    }
    w2s_img[s] = pack8(v);
  }
  // W1 image slots: [g8][chunk19][ks4][ft2][lane64]
  for (int s = tid; s < 77824; s += nthr) {
    const int g = s / 9728, r = s - g * 9728;
    const int chunk = r >> 9, r2 = r & 511;
    const int ks = r2 >> 7, ft = (r2 >> 6) & 1, l = r2 & 63;
    const int f  = chunk * 32 + ft * 16 + (l & 15);
    const int d0 = ks * 32 + ((l >> 4) << 3);
    float v[8];
    if (f < H1) {
      const float* p = W1 + ((size_t)g * H1 + f) * DIN + d0;
      f32x4 a0 = *(const f32x4*)p, a1 = *(const f32x4*)(p + 4);
      v[0]=a0[0];v[1]=a0[1];v[2]=a0[2];v[3]=a0[3];
      v[4]=a1[0];v[5]=a1[1];v[6]=a1[2];v[7]=a1[3];
    } else {
#pragma unroll
      for (int j = 0; j < 8; ++j) v[j] = 0.f;
    }
    w1_img[s] = pack8(v);
  }
  // W2a image slots: [g8][ct16][lane64]
  for (int s = tid; s < 8192; s += nthr) {
    const int g = s >> 10, ct = (s >> 6) & 15, l = s & 63;
    const int c  = ct * 32 + (l & 31);
    const int a0 = (l >> 5) << 3;
    float v[8];
    if (c < H2) {
      const float* p = W2a + ((size_t)g * H2 + c) * ACT + a0;
      f32x4 x0 = *(const f32x4*)p, x1 = *(const f32x4*)(p + 4);
      v[0]=x0[0];v[1]=x0[1];v[2]=x0[2];v[3]=x0[3];
      v[4]=x1[0];v[5]=x1[1];v[6]=x1[2];v[7]=x1[3];
    } else {
#pragma unroll
      for (int j = 0; j < 8; ++j) v[j] = 0.f;
    }
    w2a_img[s] = pack8(v);
  }
  // b1 image: [g8][768]
  for (int s = tid; s < 1536; s += nthr) {
    const int g = s / 192, f0 = (s - g * 192) * 4;
    f32x4 v;
    if (f0 < H1) v = *(const f32x4*)(b1 + g * H1 + f0);
    else { v[0]=0.f;v[1]=0.f;v[2]=0.f;v[3]=0.f; }
    b1p[s] = v;
  }
  // b2s image: [512]
  for (int s = tid; s < 128; s += nthr) {
    const int c0 = s * 4;
    f32x4 v;
    if (c0 < H2) v = *(const f32x4*)(b2s + c0);
    else { v[0]=0.f;v[1]=0.f;v[2]=0.f;v[3]=0.f; }
    b2sp[s] = v;
  }
  // W3 image: [g8][512]
  for (int s = tid; s < 1024; s += nthr) {
    const int g = s >> 7, c0 = (s & 127) * 4;
    f32x4 v;
    if (c0 < H2) v = *(const f32x4*)(W3 + g * H2 + c0);
    else { v[0]=0.f;v[1]=0.f;v[2]=0.f;v[3]=0.f; }
    w3p[s] = v;
  }
}

// ---------------- fused kernel: 2-chunk phases, counted vmcnt ----------------
__global__ __launch_bounds__(NTHR, 2) void critic_fused(
    const float* __restrict__ state, const float* __restrict__ action,
    const int* __restrict__ idx, const float* __restrict__ b3,
    const char* __restrict__ ws, float* __restrict__ out)
{
  extern __shared__ char smem[];
  const int tid = threadIdx.x, lane = tid & 63, w = tid >> 6;
  const int s0 = blockIdx.x * BT;
  int* idx_lds = (int*)(smem + LDS_IDX);
  float* b1lds = (float*)(smem + LDS_B1);
  float* red   = (float*)(smem + LDS_RED);

  const unsigned short* w2simg = (const unsigned short*)(ws + OFF_W2S);
  const unsigned short* w2aimg = (const unsigned short*)(ws + OFF_W2A);
  const float* b2sp = (const float*)(ws + OFF_B2S);
  const float* w3p  = (const float*)(ws + OFF_W3);
  const char* w1b   = ws + OFF_W1;

  if (tid < BT) idx_lds[tid] = idx[s0 + tid];

  // state B-frags (16x16x32: sample = lane&15, k = (lane>>4)*8+j)
  short8 bs[4];
  {
    const float* sp = state + (size_t)(s0 + w * 16 + (lane & 15)) * DIN + ((lane >> 4) << 3);
#pragma unroll
    for (int ks = 0; ks < 4; ++ks) {
      float v[8];
      f32x4 t0 = *(const f32x4*)(sp + ks * 32), t1 = *(const f32x4*)(sp + ks * 32 + 4);
      v[0]=t0[0];v[1]=t0[1];v[2]=t0[2];v[3]=t0[3];
      v[4]=t1[0];v[5]=t1[1];v[6]=t1[2];v[7]=t1[3];
      bs[ks] = pack8(v);
    }
  }
  // action B-frags (32x32x16: sample = lane&31, k = (lane>>5)*8+j)
  short8 bact[4];
#pragma unroll
  for (int nt = 0; nt < 4; ++nt) {
    const float* ap = action + (size_t)(s0 + nt * 32 + (lane & 31)) * ACT + ((lane >> 5) << 3);
    float v[8];
    f32x4 a0 = *(const f32x4*)ap, a1 = *(const f32x4*)(ap + 4);
    v[0]=a0[0];v[1]=a0[1];v[2]=a0[2];v[3]=a0[3];
    v[4]=a1[0];v[5]=a1[1];v[6]=a1[2];v[7]=a1[3];
    bact[nt] = pack8(v);
  }
  // b1 image -> LDS (3 DMA)
#pragma unroll
  for (int u = 0; u < 3; ++u)
    stage1k(LDS_B1 + (unsigned)(u * 8192 + tid * 16), ws + OFF_B1 + u * 8192 + tid * 16);

  __syncthreads();   // full drain: idx, b1 landed
  const int g_lo = idx_lds[0], g_hi = idx_lds[BT - 1];
  const int myg  = idx_lds[w * 16 + (lane & 15)];
  const int nsides = (g_hi > g_lo) ? 2 : 1;

  // acc init: h2a = W2a[g].action, per-sample masked (prologue; self-draining)
  f32x16 acc[2][4];
#pragma unroll
  for (int a = 0; a < 2; ++a)
#pragma unroll
    for (int n = 0; n < 4; ++n)
#pragma unroll
      for (int r = 0; r < 16; ++r) acc[a][n][r] = 0.f;
  for (int g = g_lo; g <= g_hi; ++g) {
#pragma unroll
    for (int cti = 0; cti < 2; ++cti) {
      short8 af = *(const short8*)(w2aimg + (((size_t)g * 16 + w * 2 + cti) * 64 + lane) * 8);
#pragma unroll
      for (int nt = 0; nt < 4; ++nt) {
        f32x16 z;
#pragma unroll
        for (int r = 0; r < 16; ++r) z[r] = 0.f;
        f32x16 t = __builtin_amdgcn_mfma_f32_32x32x16_bf16(af, bact[nt], z, 0, 0, 0);
        const bool p = (idx_lds[nt * 32 + (lane & 31)] == g);
#pragma unroll
        for (int r = 0; r < 16; ++r) acc[cti][nt][r] = p ? t[r] : acc[cti][nt][r];
      }
    }
  }
  __builtin_amdgcn_sched_barrier(0);

  // helpers ------------------------------------------------------------
  auto loadA = [&](int c, short8 af[2][2]) {
#pragma unroll
    for (int t = 0; t < 2; ++t)
#pragma unroll
      for (int cti = 0; cti < 2; ++cti)
        af[t][cti] = *(const short8*)(w2simg + ((((size_t)c * 2 + t) * 16 + w * 2 + cti) * 64 + lane) * 8);
  };
  auto stageW1 = [&](int c) {
    const int cs = c > (NCHUNK - 1) ? (NCHUNK - 1) : c;
    const unsigned bb = (unsigned)((c & 3) * 2);
    stage1k(LDS_W1 + (bb + 0) * 8192u + (unsigned)(tid * 16),
            w1b + ((size_t)(g_lo * NCHUNK + cs)) * 8192 + tid * 16);
    stage1k(LDS_W1 + (bb + 1) * 8192u + (unsigned)(tid * 16),
            w1b + ((size_t)(g_hi * NCHUNK + cs)) * 8192 + tid * 16);
  };
  auto consume = [&](int c, short8 af[2][2]) {
    short8 bf[2][4];
    const unsigned hb = LDS_H1 + (unsigned)((c & 3) * 8192);
#pragma unroll
    for (int t = 0; t < 2; ++t)
#pragma unroll
      for (int nt = 0; nt < 4; ++nt)
        bf[t][nt] = *(const short8*)(smem + hb + (unsigned)(((t * 4 + nt) * 64 + lane) * 16));
    __builtin_amdgcn_s_setprio(1);
#pragma unroll
    for (int t = 0; t < 2; ++t)
#pragma unroll
      for (int cti = 0; cti < 2; ++cti)
#pragma unroll
        for (int nt = 0; nt < 4; ++nt)
          acc[cti][nt] = __builtin_amdgcn_mfma_f32_32x32x16_bf16(af[t][cti], bf[t][nt], acc[cti][nt], 0, 0, 0);
    __builtin_amdgcn_s_setprio(0);
  };
  auto produce = [&](int c) {
    f32x4 kept[2];
#pragma unroll
    for (int f = 0; f < 2; ++f) { kept[f][0]=0.f;kept[f][1]=0.f;kept[f][2]=0.f;kept[f][3]=0.f; }
    for (int sd = 0; sd < nsides; ++sd) {
      const int g = sd ? g_hi : g_lo;
      f32x4 a1[2];
#pragma unroll
      for (int f = 0; f < 2; ++f) { a1[f][0]=0.f;a1[f][1]=0.f;a1[f][2]=0.f;a1[f][3]=0.f; }
      const unsigned wb = LDS_W1 + (unsigned)(((c & 3) * 2 + sd) * 8192);
#pragma unroll
      for (int ks = 0; ks < 4; ++ks)
#pragma unroll
        for (int ft = 0; ft < 2; ++ft) {
          short8 aw = *(const short8*)(smem + wb + (unsigned)(((ks * 2 + ft) * 64 + lane) * 16));
          a1[ft] = __builtin_amdgcn_mfma_f32_16x16x32_bf16(aw, bs[ks], a1[ft], 0, 0, 0);
        }
      if (myg == g) { kept[0] = a1[0]; kept[1] = a1[1]; }
    }
    const int kloc = (lane >> 4) << 2, khalf = lane >> 5;
    const int nt = w >> 1, s32 = (w & 1) * 16 + (lane & 15);
#pragma unroll
    for (int ft = 0; ft < 2; ++ft) {
      const int f0 = c * 32 + ft * 16 + kloc;
      f32x4 bv = *(const f32x4*)(b1lds + myg * B1S + f0);
      unsigned long long pk = 0;
#pragma unroll
      for (int r = 0; r < 4; ++r) {
        float hv = fmaxf(kept[ft][r] + bv[r], 0.f);
        pk |= (unsigned long long)f2bf(hv) << (16 * r);
      }
      *(unsigned long long*)(smem + LDS_H1 + (unsigned)((c & 3) * 8192 +
          (ft * 4 + nt) * 1024 + (khalf * 32 + s32) * 16 + (kloc & 7) * 2)) = pk;
    }
  };

  // prologue pipeline fill ---------------------------------------------
  short8 afA[2][2], afB[2][2];
  stageW1(0); stageW1(1); stageW1(2); stageW1(3);     // 8 DMA (oldest)
  __builtin_amdgcn_sched_barrier(0);
  loadA(0, afA);                                      // 4
  loadA(1, afB);                                      // 4
  __builtin_amdgcn_sched_barrier(0);
  asm volatile("s_waitcnt vmcnt(8)" ::: "memory");    // stages 0..3 landed (own)
  __builtin_amdgcn_sched_barrier(0);
  __builtin_amdgcn_s_barrier();                       // cross-wave: all stages landed
  produce(0);
  produce(1);
  asm volatile("s_waitcnt lgkmcnt(0)" ::: "memory");
  __builtin_amdgcn_sched_barrier(0);
  __builtin_amdgcn_s_barrier();                       // h1(0),(1) ready

  // main loop: 9 phases x 2 chunks, ONE barrier per phase ----------------
  for (int p = 0; p < NPHASE; ++p) {
    const int c0 = 2 * p, c1 = 2 * p + 1;
    stageW1(c0 + 4);                                  // oldest in this phase's queue
    stageW1(c1 + 4);
    __builtin_amdgcn_sched_barrier(0);                // pin stages before afA/afB loads
    consume(c0, afA);                                 // compiler: counted vmcnt for afA
    loadA(c0 + 2, afA);
    consume(c1, afB);
    loadA(c1 + 3 > NCHUNK - 1 ? NCHUNK - 1 : c1 + 2, afB);
    produce(c0 + 2);                                  // W1 guaranteed by prev phase's tail wait
    if (p < NPHASE - 1) produce(c1 + 2);
    asm volatile("s_waitcnt vmcnt(8)" ::: "memory");  // retire this phase's 4 stages (oldest)
    asm volatile("s_waitcnt lgkmcnt(0)" ::: "memory");
    __builtin_amdgcn_sched_barrier(0);
    __builtin_amdgcn_s_barrier();
  }
  // tail: chunk 18
  consume(NCHUNK - 1, afA);

  // epilogue: bias + relu + W3[g] dot, LDS reduce, plain store -----------
  float qp[4] = {0.f, 0.f, 0.f, 0.f};
  int gs[4];
#pragma unroll
  for (int nt = 0; nt < 4; ++nt) gs[nt] = idx_lds[nt * 32 + (lane & 31)];
#pragma unroll
  for (int cti = 0; cti < 2; ++cti) {
    const int cbase = (w * 2 + cti) * 32 + ((lane >> 5) << 2);
#pragma unroll
    for (int r = 0; r < 16; ++r) {
      const int c = cbase + (r & 3) + ((r >> 2) << 3);
      const float b2v = b2sp[c];
#pragma unroll
      for (int nt = 0; nt < 4; ++nt) {
        float v2 = fmaxf(acc[cti][nt][r] + b2v, 0.f);
        qp[nt] += v2 * w3p[gs[nt] * H2P + c];
      }
    }
  }
#pragma unroll
  for (int nt = 0; nt < 4; ++nt) {
    float v = qp[nt] + __shfl_xor(qp[nt], 32, 64);
    if (lane < 32) red[w * BT + nt * 32 + lane] = v;
  }
  __syncthreads();
  if (tid < BT) {
    float s = 0.f;
#pragma unroll
    for (int ww = 0; ww < 8; ++ww) s += red[ww * BT + tid];
    out[s0 + tid] = s + b3[idx_lds[tid]];
  }
}

extern "C" void kernel_launch(void* const* d_in, const int* in_sizes, int n_in,
                              void* d_out, int out_size, void* d_ws, size_t ws_size,
                              hipStream_t stream) {
  const float* state  = (const float*)d_in[0];
  const float* action = (const float*)d_in[1];
  const int*   idx    = (const int*)d_in[2];
  const float* W1     = (const float*)d_in[3];
  const float* b1     = (const float*)d_in[4];
  const float* W2s    = (const float*)d_in[5];
  const float* b2s    = (const float*)d_in[6];
  const float* W2a    = (const float*)d_in[7];
  const float* W3     = (const float*)d_in[8];
  const float* b3     = (const float*)d_in[9];
  float* out = (float*)d_out;
  char* ws = (char*)d_ws;

  (void)hipFuncSetAttribute((const void*)critic_fused,
                            hipFuncAttributeMaxDynamicSharedMemorySize, LDS_TOTAL);
  hipLaunchKernelGGL(prep_kernel, dim3(2048), dim3(256), 0, stream,
                     W1, b1, W2s, b2s, W2a, W3, ws);
  hipLaunchKernelGGL(critic_fused, dim3(NBLK), dim3(NTHR), LDS_TOTAL, stream,
                     state, action, idx, b3, ws, out);
}